// Round 1
// baseline (1074.077 us; speedup 1.0000x reference)
//
#include <hip/hip_runtime.h>
#include <math.h>

#define TPB 256
#define NCAT 8

// One block per row: single-pass online logsumexp + streaming top-5.
// All per-thread top-5 state lives in scalar registers (static indexing only).
__global__ __launch_bounds__(TPB) void hcl_row_kernel(
    const float* __restrict__ logits,
    const int*   __restrict__ labels,
    const int*   __restrict__ cat_labels,
    const int*   __restrict__ cmd_to_cat,
    float*       __restrict__ row_loss,
    int V)
{
    const int row  = blockIdx.x;
    const int tid  = threadIdx.x;
    const int lane = tid & 63;
    const int wave = tid >> 6;
    const float* __restrict__ rl = logits + (size_t)row * (size_t)V;

    float m = -INFINITY, s = 0.0f;
    float v0=-INFINITY, v1=-INFINITY, v2=-INFINITY, v3=-INFINITY, v4=-INFINITY;
    int   i0=0, i1=0, i2=0, i3=0, i4=0;

#define PROCESS(vin, giin) do {                                            \
        float _v = (vin); int _gi = (giin);                                \
        if (_v > m) { s = s * __expf(m - _v) + 1.0f; m = _v; }             \
        else        { s += __expf(_v - m); }                               \
        if (_v > v4) {                                                     \
            v4 = _v; i4 = _gi;                                             \
            if (v4 > v3) { float t=v3; v3=v4; v4=t; int u=i3; i3=i4; i4=u; } \
            if (v3 > v2) { float t=v2; v2=v3; v3=t; int u=i2; i2=i3; i3=u; } \
            if (v2 > v1) { float t=v1; v1=v2; v2=t; int u=i1; i1=i2; i2=u; } \
            if (v1 > v0) { float t=v0; v0=v1; v1=t; int u=i0; i0=i1; i1=u; } \
        }                                                                  \
    } while (0)

    // Row base is only 4B-aligned (V % 4 == 1): peel to 16B, float4 body, tail.
    const int mis = (int)(((size_t)rl >> 2) & 3);
    const int pre = (4 - mis) & 3;
    const int nb  = (V - pre) >> 2;
    const float4* __restrict__ body = (const float4*)(rl + pre);

    for (int i = tid; i < nb; i += TPB) {
        float4 q = body[i];
        int gi = pre + 4 * i;
        PROCESS(q.x, gi);
        PROCESS(q.y, gi + 1);
        PROCESS(q.z, gi + 2);
        PROCESS(q.w, gi + 3);
    }
    if (tid < pre) PROCESS(rl[tid], tid);
    for (int gi = pre + 4 * nb + tid; gi < V; gi += TPB) PROCESS(rl[gi], gi);
#undef PROCESS

    // ---- wave reduce (m, s) ----  (every thread saw >=3000 elems, m finite)
    #pragma unroll
    for (int off = 32; off > 0; off >>= 1) {
        float m2 = __shfl_down(m, off);
        float s2 = __shfl_down(s, off);
        float nm = fmaxf(m, m2);
        s = s * __expf(m - nm) + s2 * __expf(m2 - nm);
        m = nm;
    }

    __shared__ float sh_m[TPB/64], sh_s[TPB/64];
    __shared__ float sh_cv[TPB/64];
    __shared__ int   sh_ci[TPB/64];
    __shared__ float sh_bv;
    __shared__ int   sh_bi;

    if (lane == 0) { sh_m[wave] = m; sh_s[wave] = s; }

    // ---- block top-5: 5 rounds of block-argmax + shift-register pop ----
    float top_v[5]; int top_i[5];   // used by thread 0 only; static indices via unroll
    #pragma unroll
    for (int r = 0; r < 5; ++r) {
        float cv = v0; int ci = i0;
        #pragma unroll
        for (int off = 32; off > 0; off >>= 1) {
            float ov = __shfl_down(cv, off);
            int   oi = __shfl_down(ci, off);
            if (ov > cv || (ov == cv && oi < ci)) { cv = ov; ci = oi; }
        }
        if (lane == 0) { sh_cv[wave] = cv; sh_ci[wave] = ci; }
        __syncthreads();
        if (tid == 0) {
            float bv = sh_cv[0]; int bi = sh_ci[0];
            #pragma unroll
            for (int w = 1; w < TPB/64; ++w) {
                float ov = sh_cv[w]; int oi = sh_ci[w];
                if (ov > bv || (ov == bv && oi < bi)) { bv = ov; bi = oi; }
            }
            sh_bv = bv; sh_bi = bi;
            top_v[r] = bv; top_i[r] = bi;
        }
        __syncthreads();
        // pop the winner from its owner's list ((val,idx) pairs are unique)
        if (v0 == sh_bv && i0 == sh_bi) {
            v0=v1; i0=i1; v1=v2; i1=i2; v2=v3; i2=i3; v3=v4; i3=i4;
            v4=-INFINITY; i4=0;
        }
    }

    if (tid == 0) {
        // combine per-wave (m, s)
        float fm = sh_m[0], fs = sh_s[0];
        #pragma unroll
        for (int w = 1; w < TPB/64; ++w) {
            float m2 = sh_m[w], s2 = sh_s[w];
            float nm = fmaxf(fm, m2);
            fs = fs * __expf(fm - nm) + s2 * __expf(m2 - nm);
            fm = nm;
        }
        float lse = fm + __logf(fs);
        float nll_cmd = lse - rl[labels[row]];

        // category logits: zeros + scatter-add of top-5 values
        float cl[NCAT];
        #pragma unroll
        for (int c = 0; c < NCAT; ++c) cl[c] = 0.0f;
        #pragma unroll
        for (int r = 0; r < 5; ++r) {
            int c = cmd_to_cat[top_i[r] & 63];   // idx % 64 (TOTAL_CMDS = 64)
            float v = top_v[r];
            #pragma unroll
            for (int k = 0; k < NCAT; ++k)       // static-index scatter (no scratch)
                cl[k] += (k == c) ? v : 0.0f;
        }
        float mc = cl[0];
        #pragma unroll
        for (int c = 1; c < NCAT; ++c) mc = fmaxf(mc, cl[c]);
        float se = 0.0f;
        #pragma unroll
        for (int c = 0; c < NCAT; ++c) se += __expf(cl[c] - mc);
        float lsec = mc + __logf(se);

        int clab = cat_labels[row];
        float tgt = 0.0f;
        #pragma unroll
        for (int c = 0; c < NCAT; ++c) tgt += (c == clab) ? cl[c] : 0.0f;
        float nll_cat = lsec - tgt;

        row_loss[row] = 0.6f * nll_cmd + 0.4f * nll_cat;
    }
}

__global__ __launch_bounds__(TPB) void hcl_reduce_kernel(
    const float* __restrict__ row_loss, float* __restrict__ out, int B)
{
    const int tid = threadIdx.x;
    float s = 0.0f;
    for (int i = tid; i < B; i += TPB) s += row_loss[i];
    #pragma unroll
    for (int off = 32; off > 0; off >>= 1) s += __shfl_down(s, off);
    __shared__ float sh[TPB/64];
    const int lane = tid & 63, wave = tid >> 6;
    if (lane == 0) sh[wave] = s;
    __syncthreads();
    if (tid == 0) {
        float t = 0.0f;
        #pragma unroll
        for (int w = 0; w < TPB/64; ++w) t += sh[w];
        out[0] = t / (float)B;
    }
}

extern "C" void kernel_launch(void* const* d_in, const int* in_sizes, int n_in,
                              void* d_out, int out_size, void* d_ws, size_t ws_size,
                              hipStream_t stream) {
    const float* logits     = (const float*)d_in[0];
    const int*   labels     = (const int*)  d_in[1];
    const int*   cat_labels = (const int*)  d_in[2];
    const int*   cmd_to_cat = (const int*)  d_in[3];
    const int B = in_sizes[1];
    const int V = in_sizes[0] / B;
    float* row_loss = (float*)d_ws;   // B floats; fully written by kernel 1

    hcl_row_kernel<<<B, TPB, 0, stream>>>(logits, labels, cat_labels,
                                          cmd_to_cat, row_loss, V);
    hcl_reduce_kernel<<<1, TPB, 0, stream>>>(row_loss, (float*)d_out, B);
}

// Round 2
// 1064.781 us; speedup vs baseline: 1.0087x; 1.0087x over previous
//
#include <hip/hip_runtime.h>
#include <math.h>

#define TPB 256
#define NCAT 8
#define LOG2E  1.44269504088896f
#define LN2    0.69314718055994f
#define SHIFT  32.0f   // sum = 2^-32 * sum(e^v): overflow-safe to logit ~110

// One block per row. Single pass: branch-free sum-of-exp (constant shift, no
// online max) + streaming per-thread top-5 behind a rarely-taken branch.
__global__ __launch_bounds__(TPB) void hcl_row_kernel(
    const float* __restrict__ logits,
    const int*   __restrict__ labels,
    const int*   __restrict__ cat_labels,
    const int*   __restrict__ cmd_to_cat,
    float*       __restrict__ row_loss,
    int V)
{
    const int row  = blockIdx.x;
    const int tid  = threadIdx.x;
    const int lane = tid & 63;
    const int wave = tid >> 6;
    const float* __restrict__ rl = logits + (size_t)row * (size_t)V;

    float s0 = 0.0f, s1 = 0.0f, s2 = 0.0f, s3 = 0.0f;
    float v0=-INFINITY, v1=-INFINITY, v2=-INFINITY, v3=-INFINITY, v4=-INFINITY;
    int   i0=0, i1=0, i2=0, i3=0, i4=0;

    // 5-deep insertion; only executed when val > v4 (rare in steady state).
#define INSERT(val, gidx) do {                                               \
        v4 = (val); i4 = (gidx);                                             \
        if (v4 > v3) { float t=v3; v3=v4; v4=t; int u=i3; i3=i4; i4=u; }     \
        if (v3 > v2) { float t=v2; v2=v3; v3=t; int u=i2; i2=i3; i3=u; }     \
        if (v2 > v1) { float t=v1; v1=v2; v2=t; int u=i1; i1=i2; i2=u; }     \
        if (v1 > v0) { float t=v0; v0=v1; v1=t; int u=i0; i0=i1; i1=u; }     \
    } while (0)

    // Row base is only 4B-aligned (V % 4 == 1): peel to 16B, float4 body, tail.
    const int mis = (int)(((size_t)rl >> 2) & 3);
    const int pre = (4 - mis) & 3;
    const int nb  = (V - pre) >> 2;
    const float4* __restrict__ body = (const float4*)(rl + pre);

    for (int i = tid; i < nb; i += TPB) {
        float4 q = body[i];
        int gi = pre + 4 * i;
        // branch-free softmax-denominator accumulation (fma + v_exp + add)
        s0 += exp2f(__builtin_fmaf(q.x, LOG2E, -SHIFT));
        s1 += exp2f(__builtin_fmaf(q.y, LOG2E, -SHIFT));
        s2 += exp2f(__builtin_fmaf(q.z, LOG2E, -SHIFT));
        s3 += exp2f(__builtin_fmaf(q.w, LOG2E, -SHIFT));
        if (__builtin_expect(q.x > v4, 0)) INSERT(q.x, gi);
        if (__builtin_expect(q.y > v4, 0)) INSERT(q.y, gi + 1);
        if (__builtin_expect(q.z > v4, 0)) INSERT(q.z, gi + 2);
        if (__builtin_expect(q.w > v4, 0)) INSERT(q.w, gi + 3);
    }
    if (tid < pre) {
        float v = rl[tid];
        s0 += exp2f(__builtin_fmaf(v, LOG2E, -SHIFT));
        if (v > v4) INSERT(v, tid);
    }
    for (int gi = pre + 4 * nb + tid; gi < V; gi += TPB) {
        float v = rl[gi];
        s0 += exp2f(__builtin_fmaf(v, LOG2E, -SHIFT));
        if (v > v4) INSERT(v, gi);
    }
#undef INSERT

    // ---- wave reduce sum ----
    float s = (s0 + s1) + (s2 + s3);
    #pragma unroll
    for (int off = 32; off > 0; off >>= 1) s += __shfl_down(s, off);

    __shared__ float sh_s[TPB/64];
    __shared__ float sh_cv[TPB/64];
    __shared__ int   sh_ci[TPB/64];
    __shared__ float sh_bv;
    __shared__ int   sh_bi;

    if (lane == 0) sh_s[wave] = s;

    // ---- block top-5: 5 rounds of block-argmax + shift-register pop ----
    float top_v[5]; int top_i[5];   // thread 0 only; static indices via unroll
    #pragma unroll
    for (int r = 0; r < 5; ++r) {
        float cv = v0; int ci = i0;
        #pragma unroll
        for (int off = 32; off > 0; off >>= 1) {
            float ov = __shfl_down(cv, off);
            int   oi = __shfl_down(ci, off);
            if (ov > cv || (ov == cv && oi < ci)) { cv = ov; ci = oi; }
        }
        if (lane == 0) { sh_cv[wave] = cv; sh_ci[wave] = ci; }
        __syncthreads();
        if (tid == 0) {
            float bv = sh_cv[0]; int bi = sh_ci[0];
            #pragma unroll
            for (int w = 1; w < TPB/64; ++w) {
                float ov = sh_cv[w]; int oi = sh_ci[w];
                if (ov > bv || (ov == bv && oi < bi)) { bv = ov; bi = oi; }
            }
            sh_bv = bv; sh_bi = bi;
            top_v[r] = bv; top_i[r] = bi;
        }
        __syncthreads();
        // pop the winner from its owner's list ((val,idx) pairs are unique)
        if (v0 == sh_bv && i0 == sh_bi) {
            v0=v1; i0=i1; v1=v2; i1=i2; v2=v3; i2=i3; v3=v4; i3=i4;
            v4=-INFINITY; i4=0;
        }
    }

    if (tid == 0) {
        float fs = 0.0f;
        #pragma unroll
        for (int w = 0; w < TPB/64; ++w) fs += sh_s[w];
        // sum = 2^-SHIFT * sum(e^v)  =>  lse = (log2(sum) + SHIFT) * ln2
        float lse = (log2f(fs) + SHIFT) * LN2;
        float nll_cmd = lse - rl[labels[row]];

        // category logits: zeros + scatter-add of top-5 values
        float cl[NCAT];
        #pragma unroll
        for (int c = 0; c < NCAT; ++c) cl[c] = 0.0f;
        #pragma unroll
        for (int r = 0; r < 5; ++r) {
            int c = cmd_to_cat[top_i[r] & 63];   // idx % 64 (TOTAL_CMDS = 64)
            float v = top_v[r];
            #pragma unroll
            for (int k = 0; k < NCAT; ++k)       // static-index scatter
                cl[k] += (k == c) ? v : 0.0f;
        }
        float mc = cl[0];
        #pragma unroll
        for (int c = 1; c < NCAT; ++c) mc = fmaxf(mc, cl[c]);
        float se = 0.0f;
        #pragma unroll
        for (int c = 0; c < NCAT; ++c) se += __expf(cl[c] - mc);
        float lsec = mc + __logf(se);

        int clab = cat_labels[row];
        float tgt = 0.0f;
        #pragma unroll
        for (int c = 0; c < NCAT; ++c) tgt += (c == clab) ? cl[c] : 0.0f;
        float nll_cat = lsec - tgt;

        row_loss[row] = 0.6f * nll_cmd + 0.4f * nll_cat;
    }
}

__global__ __launch_bounds__(TPB) void hcl_reduce_kernel(
    const float* __restrict__ row_loss, float* __restrict__ out, int B)
{
    const int tid = threadIdx.x;
    float s = 0.0f;
    for (int i = tid; i < B; i += TPB) s += row_loss[i];
    #pragma unroll
    for (int off = 32; off > 0; off >>= 1) s += __shfl_down(s, off);
    __shared__ float sh[TPB/64];
    const int lane = tid & 63, wave = tid >> 6;
    if (lane == 0) sh[wave] = s;
    __syncthreads();
    if (tid == 0) {
        float t = 0.0f;
        #pragma unroll
        for (int w = 0; w < TPB/64; ++w) t += sh[w];
        out[0] = t / (float)B;
    }
}

extern "C" void kernel_launch(void* const* d_in, const int* in_sizes, int n_in,
                              void* d_out, int out_size, void* d_ws, size_t ws_size,
                              hipStream_t stream) {
    const float* logits     = (const float*)d_in[0];
    const int*   labels     = (const int*)  d_in[1];
    const int*   cat_labels = (const int*)  d_in[2];
    const int*   cmd_to_cat = (const int*)  d_in[3];
    const int B = in_sizes[1];
    const int V = in_sizes[0] / B;
    float* row_loss = (float*)d_ws;   // B floats; fully written by kernel 1

    hcl_row_kernel<<<B, TPB, 0, stream>>>(logits, labels, cat_labels,
                                          cmd_to_cat, row_loss, V);
    hcl_reduce_kernel<<<1, TPB, 0, stream>>>(row_loss, (float*)d_out, B);
}